// Round 1
// baseline (1376.235 us; speedup 1.0000x reference)
//
#include <hip/hip_runtime.h>
#include <math.h>
#include <float.h>

#define BZ 64
#define SEQ 2048
#define DIM 2048
#define NE 16
#define RR 4

// ---------------------------------------------------------------------------
// Kernel 1: partial sums of input_x over s-chunks.
// grid = BZ * DBLK * ssplit blocks, 256 threads.
// DBLK = DIM / (256 threads * 4 floats) = 2.
// Each thread accumulates a float4 over `schunk` rows of s (stride DIM).
// Coalesced: lane i reads 16B at consecutive addresses -> 1KB per wave-load.
// Deterministic (no atomics): partials written to ws, reduced in kernel 2.
// ---------------------------------------------------------------------------
__global__ __launch_bounds__(256) void partial_mean_kernel(
    const float* __restrict__ x, float* __restrict__ partial,
    int ssplit, int schunk) {
  int bid  = blockIdx.x;
  int sc   = bid % ssplit;
  int dblk = (bid / ssplit) & 1;
  int b    = bid / (ssplit * 2);
  int d    = dblk * 1024 + threadIdx.x * 4;

  const float4* src = reinterpret_cast<const float4*>(
      x + (size_t)b * SEQ * DIM + (size_t)sc * schunk * DIM + d);
  const size_t srow = DIM / 4;  // float4 stride between s rows

  float4 acc = make_float4(0.f, 0.f, 0.f, 0.f);
#pragma unroll 4
  for (int s = 0; s < schunk; ++s) {
    float4 v = src[(size_t)s * srow];
    acc.x += v.x; acc.y += v.y; acc.z += v.z; acc.w += v.w;
  }
  reinterpret_cast<float4*>(partial + ((size_t)(b * ssplit + sc)) * DIM + d)[0] = acc;
}

// ---------------------------------------------------------------------------
// Kernel 2: one block per batch row. Finish mean, both logit streams,
// softmax combine, stable top-4, scatter-mask normalize, write outputs.
// out layout: [BZ*NE] norm_score floats, then [BZ*RR] topk indices as floats.
// ---------------------------------------------------------------------------
__global__ __launch_bounds__(256) void finalize_kernel(
    const float* __restrict__ partial, const int* __restrict__ lora_idx,
    const float* __restrict__ Wb, const float* __restrict__ embed,
    const float* __restrict__ Wc, float* __restrict__ out, int ssplit) {
  int b   = blockIdx.x;
  int tid = threadIdx.x;

  int i0 = lora_idx[b * RR + 0];
  int i1 = lora_idx[b * RR + 1];
  int i2 = lora_idx[b * RR + 2];
  int i3 = lora_idx[b * RR + 3];

  float l1[NE], l2[NE];
#pragma unroll
  for (int e = 0; e < NE; ++e) { l1[e] = 0.f; l2[e] = 0.f; }

  // Each thread owns 8 d-values (strided by 256 for coalescing).
#pragma unroll
  for (int j = 0; j < DIM / 256; ++j) {
    int d = j * 256 + tid;
    float s = 0.f;
    for (int sc = 0; sc < ssplit; ++sc)
      s += partial[((size_t)(b * ssplit + sc)) * DIM + d];
    float xv = s * (1.0f / SEQ);
    float hv = (embed[(size_t)i0 * DIM + d] + embed[(size_t)i1 * DIM + d] +
                embed[(size_t)i2 * DIM + d] + embed[(size_t)i3 * DIM + d]) * 0.25f;
#pragma unroll
    for (int e = 0; e < NE; ++e) {
      l1[e] = fmaf(xv, Wb[(size_t)e * DIM + d], l1[e]);
      l2[e] = fmaf(hv, Wc[(size_t)e * DIM + d], l2[e]);
    }
  }

  // Wave (64-lane) shuffle reduce, then cross-wave via LDS.
#pragma unroll
  for (int e = 0; e < NE; ++e) {
#pragma unroll
    for (int off = 32; off >= 1; off >>= 1) {
      l1[e] += __shfl_down(l1[e], off, 64);
      l2[e] += __shfl_down(l2[e], off, 64);
    }
  }

  __shared__ float red[4][2 * NE];
  int wave = tid >> 6, lane = tid & 63;
  if (lane == 0) {
#pragma unroll
    for (int e = 0; e < NE; ++e) {
      red[wave][e]      = l1[e];
      red[wave][NE + e] = l2[e];
    }
  }
  __syncthreads();

  if (tid == 0) {
    float L1[NE], L2[NE];
#pragma unroll
    for (int e = 0; e < NE; ++e) {
      L1[e] = red[0][e] + red[1][e] + red[2][e] + red[3][e];
      L2[e] = red[0][NE + e] + red[1][NE + e] + red[2][NE + e] + red[3][NE + e];
    }

    // softmax(logits1) + softmax(logits2)
    float m1 = -FLT_MAX, m2 = -FLT_MAX;
#pragma unroll
    for (int e = 0; e < NE; ++e) { m1 = fmaxf(m1, L1[e]); m2 = fmaxf(m2, L2[e]); }
    float s1 = 0.f, s2 = 0.f;
    float p1[NE], p2[NE];
#pragma unroll
    for (int e = 0; e < NE; ++e) {
      p1[e] = __expf(L1[e] - m1); s1 += p1[e];
      p2[e] = __expf(L2[e] - m2); s2 += p2[e];
    }
    float comb[NE];
#pragma unroll
    for (int e = 0; e < NE; ++e) comb[e] = p1[e] / s1 + p2[e] / s2;

    // Stable descending top-4 (ties -> lowest index), matching jax.lax.top_k.
    int tk[RR];
    bool chosen[NE];
#pragma unroll
    for (int e = 0; e < NE; ++e) chosen[e] = false;
#pragma unroll
    for (int r = 0; r < RR; ++r) {
      float best = -FLT_MAX;
      int bi = 0;
      for (int e = 0; e < NE; ++e) {
        if (!chosen[e] && comb[e] > best) { best = comb[e]; bi = e; }
      }
      chosen[bi] = true;
      tk[r] = bi;
    }

    // score = softmax(comb); masked normalize.
    float mc = -FLT_MAX;
#pragma unroll
    for (int e = 0; e < NE; ++e) mc = fmaxf(mc, comb[e]);
    float sc_sum = 0.f;
    float sc[NE];
#pragma unroll
    for (int e = 0; e < NE; ++e) { sc[e] = __expf(comb[e] - mc); sc_sum += sc[e]; }
    float msum = 0.f;
#pragma unroll
    for (int e = 0; e < NE; ++e) {
      sc[e] /= sc_sum;
      if (chosen[e]) msum += sc[e];
    }
    float denom = fmaxf(msum, FLT_EPSILON);
#pragma unroll
    for (int e = 0; e < NE; ++e)
      out[b * NE + e] = chosen[e] ? sc[e] / denom : 0.0f;
#pragma unroll
    for (int r = 0; r < RR; ++r)
      out[BZ * NE + b * RR + r] = (float)tk[r];
  }
}

extern "C" void kernel_launch(void* const* d_in, const int* in_sizes, int n_in,
                              void* d_out, int out_size, void* d_ws, size_t ws_size,
                              hipStream_t stream) {
  const float* x     = (const float*)d_in[0];
  const int*   idx   = (const int*)d_in[1];
  const float* Wb    = (const float*)d_in[2];
  const float* embed = (const float*)d_in[3];
  const float* Wc    = (const float*)d_in[4];
  float* out     = (float*)d_out;
  float* partial = (float*)d_ws;

  // s-split for occupancy: 16 chunks -> 2048 blocks (32 waves/CU).
  // Shrink if workspace is tight (needs BZ*ssplit*DIM*4 bytes; 16 -> 8 MB).
  int ssplit = 16;
  while (ssplit > 1 && (size_t)BZ * ssplit * DIM * sizeof(float) > ws_size)
    ssplit >>= 1;
  int schunk = SEQ / ssplit;

  partial_mean_kernel<<<dim3(BZ * 2 * ssplit), dim3(256), 0, stream>>>(
      x, partial, ssplit, schunk);
  finalize_kernel<<<dim3(BZ), dim3(256), 0, stream>>>(
      partial, idx, Wb, embed, Wc, out, ssplit);
}